// Round 6
// baseline (177.744 us; speedup 1.0000x reference)
//
#include <hip/hip_runtime.h>

// Problem constants (match reference)
#define NN 50000
#define NE 800000
#define NG 512
#define INF_ 128
#define OUTF 64
#define CAP 64          // max in-degree capacity (Poisson(16): P(deg>64) ~ 1e-20)

// ---- R20 deterministic-slot bucketed adjacency build ----
// Each (chunk,bucket) owns a FIXED 80-slot segment of ebuf:
//   ebuf[bb*20000 + chunk*80 + j],  j < cnts[chunk][bb]
// (mean fill 32.8, 80 = +8.3 sigma). No global atomics, no memset dispatch.
#define NPB 98          // number of dst buckets (512 nodes each)
#define BSHIFT 9
#define BNODES 512
#define SEG 80          // slots per (chunk,bucket) segment
#define BSTRIDE (NCHUNK * SEG)   // 20000 slots per bucket
#define NCHUNK 250
#define BCH 3200        // edges per chunk (250*3200 = 800000)

// R19: GEMM tile 128 rows. 391 GEMM blocks + 250 bucket blocks.
#define GEMM2_BLOCKS ((NN + 127) / 128)       // 391
// grid: b<500: even -> bucket chunk b>>1, odd -> gemm b>>1 (0..249)
//       b in [500,641) -> gemm 250+(b-500)
#define FRONT_BLOCKS 641

#define XSTRIDE 136     // shorts per staged row (128 + 8 pad; keeps b128 16B-aligned)

__device__ __forceinline__ unsigned short f2bf(float f) {
    unsigned int u = __float_as_uint(f);
    unsigned int r = (u + 0x7fffu + ((u >> 16) & 1u)) >> 16;   // RNE
    return (unsigned short)r;
}
__device__ __forceinline__ float bf2f(unsigned int lo16) {
    return __uint_as_float(lo16 << 16);
}

using bf16x8 = __attribute__((ext_vector_type(8))) __bf16;
using f32x4  = __attribute__((ext_vector_type(4))) float;

// ---------------- Fused front: edge bucketing + MFMA GEMM -----------------
__global__ __launch_bounds__(256) void k_front(
    const int* __restrict__ ei, int* __restrict__ cnts,
    unsigned int* __restrict__ ebuf, float* __restrict__ gden,
    float* __restrict__ g_num,
    const float* __restrict__ x, const float* __restrict__ W,
    const float* __restrict__ att_src, const float* __restrict__ att_dst,
    unsigned short* __restrict__ hb, float* __restrict__ a_s,
    float* __restrict__ a_d)
{
    __shared__ union {
        struct {
            unsigned short Wt[OUTF * XSTRIDE];    // 17.4 KB (bf16 W^T: [col][k])
            unsigned short Xs[128 * XSTRIDE];     // 34.8 KB (bf16 x tile: [row][k])
        } g;
        struct {
            int hist[128];                    // per-bucket count -> cursor
            int bofs[128];                    // exclusive start
            unsigned int pk[BCH];             // packed edges (chunk order)
            unsigned int ord[BCH];            // packed edges (bucket order)
        } b;
    } sm;

    {   // zero gden/g_num (needs first 131 blocks; grid = 641)
        int idx = blockIdx.x * 256 + threadIdx.x;
        if (idx < NG) gden[idx] = 0.f;
        else if (idx < NG + NG * OUTF) g_num[idx - NG] = 0.f;
    }

    const int t = threadIdx.x;
    int gemmIdx;
    if (blockIdx.x < 500) {
        const int pr = blockIdx.x >> 1;
        if ((blockIdx.x & 1) == 0) {
            // ---------------- bucket chunk pr ----------------
            if (t < 128) sm.b.hist[t] = 0;
            __syncthreads();

            const int e0 = pr * BCH;
            for (int i = t; i < BCH; i += 256) {
                int e = e0 + i;
                int s = ei[e];
                int d = ei[NE + e];
                int bb = d >> BSHIFT;                       // 0..97
                unsigned int v = ((unsigned int)bb << 25) |
                                 ((unsigned int)(d & (BNODES - 1)) << 16) |
                                 (unsigned int)s;           // s < 65536
                sm.b.pk[i] = v;
                atomicAdd(&sm.b.hist[bb], 1);
            }
            __syncthreads();

            // wave-0 shfl scan over 128 buckets; 0 barriers inside.
            // R20: counts written plainly to cnts[pr][*]; no global atomics.
            if (t < 64) {
                int c0 = sm.b.hist[2 * t];
                int c1 = sm.b.hist[2 * t + 1];
                int p  = c0 + c1;
                int ip = p;
                #pragma unroll
                for (int m = 1; m < 64; m <<= 1) {
                    int o = __shfl_up(ip, m, 64);
                    if (t >= m) ip += o;
                }
                int epair = ip - p;            // exclusive pair base
                int ex0 = epair;
                int ex1 = epair + c0;
                if (2 * t     < NPB) cnts[pr * NPB + 2 * t]     = min(c0, SEG);
                if (2 * t + 1 < NPB) cnts[pr * NPB + 2 * t + 1] = min(c1, SEG);
                sm.b.bofs[2 * t]     = ex0;
                sm.b.bofs[2 * t + 1] = ex1;
                sm.b.hist[2 * t]     = ex0;    // scatter cursor
                sm.b.hist[2 * t + 1] = ex1;
            }
            __syncthreads();

            // scatter into bucket order
            for (int i = t; i < BCH; i += 256) {
                unsigned int v = sm.b.pk[i];
                int bb = v >> 25;
                int p = atomicAdd(&sm.b.hist[bb], 1);
                sm.b.ord[p] = v;
            }
            __syncthreads();

            // copy out: consecutive i -> consecutive global addrs per run,
            // into the (pr,bb) fixed segment
            for (int i = t; i < BCH; i += 256) {
                unsigned int v = sm.b.ord[i];
                int bb = v >> 25;
                int gp = i - sm.b.bofs[bb];
                if (gp < SEG) ebuf[bb * BSTRIDE + pr * SEG + gp] = v;
            }
            return;
        }
        gemmIdx = pr;                          // 0..249
    } else {
        gemmIdx = 250 + (blockIdx.x - 500);    // 250..390
    }

    // ---------------- GEMM part (MFMA, 128-row tile) ----------------
    const int n0 = gemmIdx * 128;

    // stage W transposed as bf16: Wt[col][k]; coalesced float4 global reads
    #pragma unroll
    for (int it = 0; it < 8; it++) {
        int i = it * 256 + t;                  // 2048 float4 granules
        int k  = i >> 4;                       // W row (k), 16 granules/row
        int n4 = (i & 15) * 4;                 // W col base
        float4 v = ((const float4*)W)[i];
        sm.g.Wt[(n4 + 0) * XSTRIDE + k] = f2bf(v.x);
        sm.g.Wt[(n4 + 1) * XSTRIDE + k] = f2bf(v.y);
        sm.g.Wt[(n4 + 2) * XSTRIDE + k] = f2bf(v.z);
        sm.g.Wt[(n4 + 3) * XSTRIDE + k] = f2bf(v.w);
    }

    // stage x tile: 128 rows x 128 cols, coalesced float4 loads -> bf16 LDS
    #pragma unroll
    for (int it = 0; it < 16; it++) {
        int idx = it * 256 + t;                // float4 granule id (0..4095)
        int row = idx >> 5;                    // 32 float4 per row
        int c4  = idx & 31;
        int n = n0 + row;
        if (n > NN - 1) n = NN - 1;            // clamp tail (stores guarded)
        float4 v = ((const float4*)(x + (size_t)n * INF_))[c4];
        ushort4 b;
        b.x = f2bf(v.x); b.y = f2bf(v.y); b.z = f2bf(v.z); b.w = f2bf(v.w);
        *(ushort4*)&sm.g.Xs[row * XSTRIDE + c4 * 4] = b;
    }
    __syncthreads();

    const int lane = t & 63;
    const int w    = t >> 6;        // wave id: output rows w*32..w*32+31
    const int q    = lane & 15;
    const int h4   = lane >> 4;     // k-octet selector

    f32x4 acc[2][4];
    #pragma unroll
    for (int rt = 0; rt < 2; rt++)
        #pragma unroll
        for (int ct = 0; ct < 4; ct++) acc[rt][ct] = (f32x4){0.f, 0.f, 0.f, 0.f};

    const unsigned short* Ax0 = &sm.g.Xs[(w * 32 + q) * XSTRIDE + h4 * 8];
    const unsigned short* Ax1 = &sm.g.Xs[(w * 32 + 16 + q) * XSTRIDE + h4 * 8];
    const unsigned short* Bw  = &sm.g.Wt[q * XSTRIDE + h4 * 8];

    #pragma unroll
    for (int ks = 0; ks < 4; ks++) {           // K = 4 x 32
        bf16x8 a0 = *(const bf16x8*)(Ax0 + ks * 32);
        bf16x8 a1 = *(const bf16x8*)(Ax1 + ks * 32);
        #pragma unroll
        for (int ct = 0; ct < 4; ct++) {       // 4 col-tiles of 16
            bf16x8 bv = *(const bf16x8*)(Bw + ct * 16 * XSTRIDE + ks * 32);
            acc[0][ct] = __builtin_amdgcn_mfma_f32_16x16x32_bf16(a0, bv, acc[0][ct], 0, 0, 0);
            acc[1][ct] = __builtin_amdgcn_mfma_f32_16x16x32_bf16(a1, bv, acc[1][ct], 0, 0, 0);
        }
    }

    // epilogue: lane holds C[row = w*32 + rt*16 + h4*4 + r][col = ct*16 + q]
    float atts[4], attd[4];
    #pragma unroll
    for (int ct = 0; ct < 4; ct++) {
        int head = 2 * ct + (q >> 3);
        atts[ct] = att_src[head * 8 + (q & 7)];
        attd[ct] = att_dst[head * 8 + (q & 7)];
    }

    #pragma unroll
    for (int rt = 0; rt < 2; rt++) {
        #pragma unroll
        for (int r = 0; r < 4; r++) {
            const int n = n0 + w * 32 + rt * 16 + h4 * 4 + r;
            const bool valid = (n < NN);
            if (valid) {
                #pragma unroll
                for (int ct = 0; ct < 4; ct++)
                    hb[(size_t)n * OUTF + ct * 16 + q] = f2bf(acc[rt][ct][r]);
            }
            // per-head projections: reduce over the 8 lanes of each head group
            float ps[4], pd[4];
            #pragma unroll
            for (int ct = 0; ct < 4; ct++) {
                float v = acc[rt][ct][r];
                ps[ct] = v * atts[ct];
                pd[ct] = v * attd[ct];
            }
            #pragma unroll
            for (int m = 1; m < 8; m <<= 1) {
                #pragma unroll
                for (int ct = 0; ct < 4; ct++) {
                    ps[ct] += __shfl_xor(ps[ct], m, 64);
                    pd[ct] += __shfl_xor(pd[ct], m, 64);
                }
            }
            if (valid && (q & 7) == 0) {
                #pragma unroll
                for (int ct = 0; ct < 4; ct++) {
                    int head = 2 * ct + (q >> 3);
                    a_s[n * 8 + head] = ps[ct];
                    a_d[n * 8 + head] = pd[ct];
                }
            }
        }
    }
}

// ---------------- Phase B: dense adjacency build from segments -------------
// 2 blocks per bucket; coalesced scan of the bucket's 250 fixed segments,
// validity from LDS-cached per-segment counts.
#define BHALF 256
__global__ __launch_bounds__(256) void k_build(
    const unsigned int* __restrict__ ebuf, const int* __restrict__ cnts,
    int* __restrict__ deg, unsigned short* __restrict__ adj)
{
    __shared__ unsigned short ladj[BHALF * CAP];  // 32 KB
    __shared__ int ldeg[BHALF];                   // 1 KB
    __shared__ int scnt[NCHUNK];                  // 1 KB

    const int b    = blockIdx.x >> 1;
    const int half = blockIdx.x & 1;
    const int rlo  = half * BHALF;
    const int t    = threadIdx.x;

    if (t < BHALF) ldeg[t] = 0;
    for (int i = t; i < NCHUNK; i += 256) scnt[i] = cnts[i * NPB + b];
    __syncthreads();

    const unsigned int* eb = ebuf + (size_t)b * BSTRIDE;
    for (int i = t; i < BSTRIDE; i += 256) {
        int ch = i / SEG;
        int j  = i - ch * SEG;
        unsigned int v = eb[i];
        if (j < scnt[ch]) {
            int drel = (v >> 16) & (BNODES - 1);
            unsigned int rr = (unsigned int)(drel - rlo);
            if (rr < BHALF) {
                int p = atomicAdd(&ldeg[rr], 1);
                if (p < CAP) ladj[rr * CAP + p] = (unsigned short)(v & 0xffffu);
            }
        }
    }
    __syncthreads();

    const int n0 = b * BNODES + rlo;
    if (t < BHALF) {
        int n = n0 + t;
        if (n < NN) deg[n] = ldeg[t];
    }
    // adj rows: 256 rows x 128 B, coalesced uint4 stores (rows w/ deg<CAP
    // carry garbage past deg[n] -- never read by consumers)
    for (int i = t; i < BHALF * CAP / 8; i += 256) {
        int n = n0 + (i >> 3);
        if (n < NN)
            ((uint4*)(adj + (size_t)n * CAP))[i & 7] = ((const uint4*)ladj)[i];
    }
}

// ---------------- GAT aggregation: wave = 8 edge-slots x 8 col-octets ------
__global__ __launch_bounds__(256) void k_aggr(
    const unsigned short* __restrict__ hb, const float* __restrict__ a_s,
    const float* __restrict__ a_d, const int* __restrict__ deg,
    const unsigned short* __restrict__ adj, const float* __restrict__ bias,
    const float* __restrict__ w_rel, const float* __restrict__ w_root,
    float* __restrict__ out, float* __restrict__ t_rel, float* __restrict__ t_root)
{
    const int wid  = threadIdx.x >> 6;
    const int lane = threadIdx.x & 63;
    const int g    = lane >> 3;     // edge slot 0..7
    const int c8   = lane & 7;      // head / col-octet 0..7
    const int n    = blockIdx.x * 4 + wid;
    if (n >= NN) return;

    const float ad_n = a_d[n * 8 + c8];

    float acc[8];
    #pragma unroll
    for (int k = 0; k < 8; k++) acc[k] = 0.f;
    float den = 0.f;

    // self-loop handled by edge slot 0
    if (g == 0) {
        float e0 = a_s[n * 8 + c8] + ad_n;
        e0 = e0 > 0.f ? e0 : 0.2f * e0;
        float ex0 = __expf(e0);
        uint4 hv = *(const uint4*)(hb + (size_t)n * OUTF + c8 * 8);
        acc[0] = ex0 * bf2f(hv.x & 0xffffu); acc[1] = ex0 * bf2f(hv.x >> 16);
        acc[2] = ex0 * bf2f(hv.y & 0xffffu); acc[3] = ex0 * bf2f(hv.y >> 16);
        acc[4] = ex0 * bf2f(hv.z & 0xffffu); acc[5] = ex0 * bf2f(hv.z >> 16);
        acc[6] = ex0 * bf2f(hv.w & 0xffffu); acc[7] = ex0 * bf2f(hv.w >> 16);
        den = ex0;
    }

    const int cnt = min(deg[n], CAP);
    const unsigned short* lst = adj + (size_t)n * CAP;

    // preload indices for 4 strided slots, then issue all gathers
    int sv[4];
    #pragma unroll
    for (int ii = 0; ii < 4; ii++) {
        int i = g + ii * 8;
        sv[ii] = (i < cnt) ? (int)lst[i] : -1;
    }
    float asl[4]; uint4 hvl[4];
    #pragma unroll
    for (int ii = 0; ii < 4; ii++) {
        int s = (sv[ii] >= 0) ? sv[ii] : n;    // clamp to hot self row
        asl[ii] = a_s[s * 8 + c8];
        hvl[ii] = *(const uint4*)(hb + (size_t)s * OUTF + c8 * 8);
    }
    #pragma unroll
    for (int ii = 0; ii < 4; ii++) {
        float e = asl[ii] + ad_n;
        e = e > 0.f ? e : 0.2f * e;
        float ex = (sv[ii] >= 0) ? __expf(e) : 0.f;
        uint4 hv = hvl[ii];
        acc[0] = fmaf(ex, bf2f(hv.x & 0xffffu), acc[0]);
        acc[1] = fmaf(ex, bf2f(hv.x >> 16),     acc[1]);
        acc[2] = fmaf(ex, bf2f(hv.y & 0xffffu), acc[2]);
        acc[3] = fmaf(ex, bf2f(hv.y >> 16),     acc[3]);
        acc[4] = fmaf(ex, bf2f(hv.z & 0xffffu), acc[4]);
        acc[5] = fmaf(ex, bf2f(hv.z >> 16),     acc[5]);
        acc[6] = fmaf(ex, bf2f(hv.w & 0xffffu), acc[6]);
        acc[7] = fmaf(ex, bf2f(hv.w >> 16),     acc[7]);
        den += ex;
    }
    // rare tail (deg > 32)
    for (int i = g + 32; i < cnt; i += 8) {
        int s = lst[i];
        float as = a_s[s * 8 + c8];
        uint4 hv = *(const uint4*)(hb + (size_t)s * OUTF + c8 * 8);
        float e = as + ad_n;
        e = e > 0.f ? e : 0.2f * e;
        float ex = __expf(e);
        acc[0] = fmaf(ex, bf2f(hv.x & 0xffffu), acc[0]);
        acc[1] = fmaf(ex, bf2f(hv.x >> 16),     acc[1]);
        acc[2] = fmaf(ex, bf2f(hv.y & 0xffffu), acc[2]);
        acc[3] = fmaf(ex, bf2f(hv.y >> 16),     acc[3]);
        acc[4] = fmaf(ex, bf2f(hv.z & 0xffffu), acc[4]);
        acc[5] = fmaf(ex, bf2f(hv.z >> 16),     acc[5]);
        acc[6] = fmaf(ex, bf2f(hv.w & 0xffffu), acc[6]);
        acc[7] = fmaf(ex, bf2f(hv.w >> 16),     acc[7]);
        den += ex;
    }

    // butterfly reduce across edge slots (g bits = lane bits 3..5)
    #pragma unroll
    for (int m = 8; m < 64; m <<= 1) {
        den += __shfl_xor(den, m, 64);
        #pragma unroll
        for (int k = 0; k < 8; k++) acc[k] += __shfl_xor(acc[k], m, 64);
    }

    const float inv = 1.f / (den + 1e-16f);
    float o[8];
    #pragma unroll
    for (int k = 0; k < 8; k++) o[k] = acc[k] * inv + bias[c8 * 8 + k];

    if (g == 0) {
        float4 o0 = make_float4(o[0], o[1], o[2], o[3]);
        float4 o1 = make_float4(o[4], o[5], o[6], o[7]);
        float4* op = (float4*)(out + (size_t)n * OUTF + c8 * 8);
        op[0] = o0; op[1] = o1;
    }

    // pooling-score projections: vr = sum_j o_j*w_rel_j (cols dup across g)
    float vr = 0.f, vt = 0.f;
    #pragma unroll
    for (int k = 0; k < 8; k++) {
        vr = fmaf(o[k], w_rel[c8 * 8 + k], vr);
        vt = fmaf(o[k], w_root[c8 * 8 + k], vt);
    }
    #pragma unroll
    for (int m = 1; m < 8; m <<= 1) {
        vr += __shfl_xor(vr, m, 64);
        vt += __shfl_xor(vt, m, 64);
    }
    if (lane == 0) { t_rel[n] = vr; t_root[n] = vt; }
}

// ---------------- fused pooling: score gather + softmax-numerator pool -----
// R2 structure (1563 blocks, TLP-rich); R19: 4-deep preload in phase 1.
__global__ __launch_bounds__(256) void k_score_pool(
    const int* __restrict__ deg, const unsigned short* __restrict__ adj,
    const float* __restrict__ t_rel, const float* __restrict__ t_root,
    const float* __restrict__ pool_b, const int* __restrict__ batch,
    const float* __restrict__ out,
    float* __restrict__ gden, float* __restrict__ g_num)
{
    __shared__ float ex_s[32];
    __shared__ int   b_s[32];

    const int wid  = threadIdx.x >> 6;
    const int lane = threadIdx.x & 63;
    const int sub  = lane >> 3;     // node within wave (0..7)
    const int g    = lane & 7;      // slot
    const int base_n = blockIdx.x * 32;
    const int n    = base_n + wid * 8 + sub;

    const int cnt = (n < NN) ? min(deg[n], CAP) : 0;
    const unsigned short* lst = adj + (size_t)n * CAP;

    // 4-deep preload: indices first, then all t_rel gathers in parallel
    int sv[4];
    #pragma unroll
    for (int ii = 0; ii < 4; ii++) {
        int i = g + ii * 8;
        sv[ii] = (i < cnt) ? (int)lst[i] : -1;
    }
    float tv[4];
    #pragma unroll
    for (int ii = 0; ii < 4; ii++) {
        int s = (sv[ii] >= 0) ? sv[ii] : 0;
        tv[ii] = t_rel[s];
    }
    float acc = 0.f;
    #pragma unroll
    for (int ii = 0; ii < 4; ii++)
        acc += (sv[ii] >= 0) ? tv[ii] : 0.f;
    for (int i = g + 32; i < cnt; i += 8) acc += t_rel[lst[i]];
    #pragma unroll
    for (int m = 1; m < 8; m <<= 1) acc += __shfl_xor(acc, m, 64);

    if (g == 0) {
        const int slot = wid * 8 + sub;
        if (n < NN) {
            float ex = __expf(acc + t_root[n] + pool_b[0]);
            ex_s[slot] = ex;
            b_s[slot]  = batch[n];
        } else {
            ex_s[slot] = 0.f;
            b_s[slot]  = -1;
        }
    }
    __syncthreads();

    if (threadIdx.x == 0) {           // gden run-length flush (batch sorted)
        float racc = 0.f;
        int bcur = -1;
        for (int i = 0; i < 32; i++) {
            int b = b_s[i];
            if (b != bcur) {
                if (bcur >= 0) atomicAdd(&gden[bcur], racc);
                bcur = b; racc = 0.f;
            }
            racc += ex_s[i];
        }
        if (bcur >= 0) atomicAdd(&gden[bcur], racc);
    }

    // phase 2: wave wid accumulates its 8 nodes; lane = feature j
    const int j = lane;
    float facc = 0.f;
    int bcur = -1;
    for (int i = 0; i < 8; i++) {
        const int slot = wid * 8 + i;
        const int n2 = base_n + slot;
        if (n2 >= NN) break;
        int b = b_s[slot];                         // wave-uniform
        if (b != bcur) {
            if (bcur >= 0) atomicAdd(&g_num[bcur * OUTF + j], facc);
            bcur = b; facc = 0.f;
        }
        facc = fmaf(out[(size_t)n2 * OUTF + j], ex_s[slot], facc);
    }
    if (bcur >= 0) atomicAdd(&g_num[bcur * OUTF + j], facc);
}

// ---------------- g[b,j] = g_num[b,j] / (gden[b] + eps) --------------------
__global__ __launch_bounds__(256) void k_gfinal(
    const float* __restrict__ g_num, const float* __restrict__ gden,
    float* __restrict__ g)
{
    int i = blockIdx.x * 256 + threadIdx.x;
    if (i < NG * OUTF) g[i] = g_num[i] / (gden[i >> 6] + 1e-16f);
}

extern "C" void kernel_launch(void* const* d_in, const int* in_sizes, int n_in,
                              void* d_out, int out_size, void* d_ws, size_t ws_size,
                              hipStream_t stream)
{
    const float* x        = (const float*)d_in[0];
    const int*   ei       = (const int*)  d_in[1];
    const int*   batch    = (const int*)  d_in[2];
    const float* W        = (const float*)d_in[3];
    const float* att_src  = (const float*)d_in[4];
    const float* att_dst  = (const float*)d_in[5];
    const float* bias     = (const float*)d_in[6];
    const float* w_rel    = (const float*)d_in[7];
    const float* pool_b   = (const float*)d_in[8];
    const float* w_root   = (const float*)d_in[9];

    float* out_nodes = (float*)d_out;                       // [NN,64]
    float* g_out     = (float*)d_out + (size_t)NN * OUTF;   // [NG,64]

    // workspace layout (bytes)
    char* base = (char*)d_ws;
    unsigned short* hb = (unsigned short*)(base);           //  6,400,000 B
    float* a_s       = (float*)(base +  6400000);           //  1,600,000 B
    float* a_d       = (float*)(base +  8000000);           //  1,600,000 B
    float* t_rel     = (float*)(base +  9600000);           //    200,000 B
    float* t_root    = (float*)(base +  9800000);           //    200,000 B
    float* gden      = (float*)(base + 10000000);           //      2,048 B
    float* g_num     = (float*)(base + 10002048);           //    131,072 B
    int*   deg       = (int*)  (base + 10133120);           //    200,000 B
    unsigned short* adjl = (unsigned short*)(base + 10333120); // 6,400,000 B
    unsigned int* ebuf = (unsigned int*)(base + 16733120);  //  7,840,000 B (98*250*80*4)
    int*   cnts      = (int*)  (base + 24573120);           //     98,000 B (250*98*4)
    // total: 24,671,120 B

    // R20: no memset needed -- cnts fully written by k_front bucket blocks,
    // gden/g_num zeroed inside k_front, deg written densely by k_build.

    k_front<<<FRONT_BLOCKS, 256, 0, stream>>>(
        ei, cnts, ebuf, gden, g_num,
        x, W, att_src, att_dst, hb, a_s, a_d);
    k_build<<<NPB * 2, 256, 0, stream>>>(ebuf, cnts, deg, adjl);
    k_aggr<<<(NN + 3) / 4, 256, 0, stream>>>(hb, a_s, a_d, deg, adjl, bias,
                                             w_rel, w_root, out_nodes, t_rel, t_root);
    k_score_pool<<<(NN + 31) / 32, 256, 0, stream>>>(deg, adjl, t_rel, t_root,
                                                     pool_b, batch, out_nodes,
                                                     gden, g_num);
    k_gfinal<<<(NG * OUTF + 255) / 256, 256, 0, stream>>>(g_num, gden, g_out);
}

// Round 7
// 160.839 us; speedup vs baseline: 1.1051x; 1.1051x over previous
//
#include <hip/hip_runtime.h>

// Problem constants (match reference)
#define NN 50000
#define NE 800000
#define NG 512
#define INF_ 128
#define OUTF 64
#define CAP 64          // max in-degree capacity (Poisson(16): P(deg>64) ~ 1e-20)

// ---- R15 bucketed adjacency build (kept) ----
#define NPB 98          // number of dst buckets (512 nodes each)
#define BSHIFT 9
#define BNODES 512
#define BCAP 9216       // per-bucket edge capacity (mean 8192, sd ~90: +11 sigma)
#define NCHUNK 250
#define BCH 3200        // edges per chunk (250*3200 = 800000)

#define GEMM_BLOCKS ((NN + 63) / 64)          // 782
// grid: blocks b<1000: (b&3)==0 -> bucket chunk b>>2, else gemm oct*3+(r-1)
//       blocks 1000..1031 -> gemm 750..781
#define FRONT_BLOCKS 1032

#define XSTRIDE 136     // shorts per staged row (128 + 8 pad; keeps b128 16B-aligned)

__device__ __forceinline__ unsigned short f2bf(float f) {
    unsigned int u = __float_as_uint(f);
    unsigned int r = (u + 0x7fffu + ((u >> 16) & 1u)) >> 16;   // RNE
    return (unsigned short)r;
}
__device__ __forceinline__ float bf2f(unsigned int lo16) {
    return __uint_as_float(lo16 << 16);
}

using bf16x8 = __attribute__((ext_vector_type(8))) __bf16;
using f32x4  = __attribute__((ext_vector_type(4))) float;

// ---------------- Fused front: edge bucketing + MFMA GEMM -----------------
// R16: scalar-FMA GEMM -> v_mfma_f32_16x16x32_bf16. W staged TRANSPOSED
// Wt[col][k] so B-fragments are contiguous b128 reads.
__global__ __launch_bounds__(256) void k_front(
    const int* __restrict__ ei, int* __restrict__ bcnt,
    unsigned int* __restrict__ ebuf, float* __restrict__ gden,
    float* __restrict__ g_num,
    const float* __restrict__ x, const float* __restrict__ W,
    const float* __restrict__ att_src, const float* __restrict__ att_dst,
    unsigned short* __restrict__ hb, float* __restrict__ a_s,
    float* __restrict__ a_d)
{
    __shared__ union {
        struct {
            unsigned short Wt[OUTF * XSTRIDE];   // 17.4 KB (bf16 W^T: [col][k])
            unsigned short Xs[64 * XSTRIDE];     // 17.4 KB (bf16 x tile: [row][k])
        } g;
        struct {
            int hist[128];                    // per-bucket count -> cursor
            int bofs[128];                    // inclusive scan -> exclusive
            int goff[128];                    // global base per bucket
            unsigned int pk[BCH];             // packed edges (chunk order)
            unsigned int ord[BCH];            // packed edges (bucket order)
        } b;
    } sm;

    {   // zero gden/g_num (needs first 131 blocks; grid = 1032)
        int idx = blockIdx.x * 256 + threadIdx.x;
        if (idx < NG) gden[idx] = 0.f;
        else if (idx < NG + NG * OUTF) g_num[idx - NG] = 0.f;
    }

    const int t = threadIdx.x;
    int gemmIdx;
    if (blockIdx.x < 1000) {
        const int oct = blockIdx.x >> 2;
        const int r   = blockIdx.x & 3;
        if (r == 0) {
            // ---------------- bucket chunk oct ----------------
            if (t < 128) sm.b.hist[t] = 0;
            __syncthreads();

            const int e0 = oct * BCH;
            for (int i = t; i < BCH; i += 256) {
                int e = e0 + i;
                int s = ei[e];
                int d = ei[NE + e];
                int bb = d >> BSHIFT;                       // 0..97
                unsigned int v = ((unsigned int)bb << 25) |
                                 ((unsigned int)(d & (BNODES - 1)) << 16) |
                                 (unsigned int)s;           // s < 65536
                sm.b.pk[i] = v;
                atomicAdd(&sm.b.hist[bb], 1);
            }
            __syncthreads();

            int cntv = 0;
            if (t < 128) {
                cntv = sm.b.hist[t];
                sm.b.bofs[t] = cntv;
                // reserve global space (one atomic per bucket per chunk)
                sm.b.goff[t] = (t < NPB) ? atomicAdd(&bcnt[t], cntv) : 0;
            }
            __syncthreads();
            // Hillis-Steele inclusive scan over 128 entries
            for (int off = 1; off < 128; off <<= 1) {
                int v2;
                if (t < 128) {
                    v2 = sm.b.bofs[t];
                    if (t >= off) v2 += sm.b.bofs[t - off];
                }
                __syncthreads();
                if (t < 128) sm.b.bofs[t] = v2;
                __syncthreads();
            }
            if (t < 128) {
                int excl = sm.b.bofs[t] - cntv;
                sm.b.bofs[t] = excl;      // exclusive start (for copy-out)
                sm.b.hist[t] = excl;      // cursor (for scatter)
            }
            __syncthreads();

            // scatter into bucket order
            for (int i = t; i < BCH; i += 256) {
                unsigned int v = sm.b.pk[i];
                int bb = v >> 25;
                int p = atomicAdd(&sm.b.hist[bb], 1);
                sm.b.ord[p] = v;
            }
            __syncthreads();

            // copy out: consecutive i -> consecutive global addrs per run
            for (int i = t; i < BCH; i += 256) {
                unsigned int v = sm.b.ord[i];
                int bb = v >> 25;
                int gp = sm.b.goff[bb] + (i - sm.b.bofs[bb]);
                if (gp < BCAP) ebuf[(size_t)bb * BCAP + gp] = v;
            }
            return;
        }
        gemmIdx = oct * 3 + (r - 1);      // 0..749
    } else {
        gemmIdx = 750 + (blockIdx.x - 1000);   // 750..781
    }

    // ---------------- GEMM part (MFMA) ----------------
    const int n0 = gemmIdx * 64;

    // stage W transposed as bf16: Wt[col][k]; coalesced float4 global reads
    #pragma unroll
    for (int it = 0; it < 8; it++) {
        int i = it * 256 + t;                  // 2048 float4 granules
        int k  = i >> 4;                       // W row (k), 16 granules/row
        int n4 = (i & 15) * 4;                 // W col base
        float4 v = ((const float4*)W)[i];
        sm.g.Wt[(n4 + 0) * XSTRIDE + k] = f2bf(v.x);
        sm.g.Wt[(n4 + 1) * XSTRIDE + k] = f2bf(v.y);
        sm.g.Wt[(n4 + 2) * XSTRIDE + k] = f2bf(v.z);
        sm.g.Wt[(n4 + 3) * XSTRIDE + k] = f2bf(v.w);
    }

    // stage x tile: 64 rows x 128 cols, coalesced float4 loads -> bf16 LDS
    #pragma unroll
    for (int it = 0; it < 8; it++) {
        int idx = it * 256 + t;                // float4 granule id
        int row = idx >> 5;                    // 32 float4 per row
        int c4  = idx & 31;
        int n = n0 + row;
        if (n > NN - 1) n = NN - 1;            // clamp tail (stores guarded)
        float4 v = ((const float4*)(x + (size_t)n * INF_))[c4];
        ushort4 b;
        b.x = f2bf(v.x); b.y = f2bf(v.y); b.z = f2bf(v.z); b.w = f2bf(v.w);
        *(ushort4*)&sm.g.Xs[row * XSTRIDE + c4 * 4] = b;
    }
    __syncthreads();

    const int lane = t & 63;
    const int w    = t >> 6;        // wave id: output rows w*16..w*16+15
    const int q    = lane & 15;
    const int h4   = lane >> 4;     // k-octet selector

    f32x4 acc[4];
    #pragma unroll
    for (int ct = 0; ct < 4; ct++) acc[ct] = (f32x4){0.f, 0.f, 0.f, 0.f};

    const unsigned short* Ax = &sm.g.Xs[(w * 16 + q) * XSTRIDE + h4 * 8];
    const unsigned short* Bw = &sm.g.Wt[q * XSTRIDE + h4 * 8];

    #pragma unroll
    for (int ks = 0; ks < 4; ks++) {           // K = 4 x 32
        bf16x8 av = *(const bf16x8*)(Ax + ks * 32);
        #pragma unroll
        for (int ct = 0; ct < 4; ct++) {       // 4 col-tiles of 16
            bf16x8 bv = *(const bf16x8*)(Bw + ct * 16 * XSTRIDE + ks * 32);
            acc[ct] = __builtin_amdgcn_mfma_f32_16x16x32_bf16(av, bv, acc[ct], 0, 0, 0);
        }
    }

    // epilogue: lane holds C[row = w*16 + h4*4 + r][col = ct*16 + q]
    float atts[4], attd[4];
    #pragma unroll
    for (int ct = 0; ct < 4; ct++) {
        int head = 2 * ct + (q >> 3);
        atts[ct] = att_src[head * 8 + (q & 7)];
        attd[ct] = att_dst[head * 8 + (q & 7)];
    }

    #pragma unroll
    for (int r = 0; r < 4; r++) {
        const int n = n0 + w * 16 + h4 * 4 + r;
        const bool valid = (n < NN);
        if (valid) {
            #pragma unroll
            for (int ct = 0; ct < 4; ct++)
                hb[(size_t)n * OUTF + ct * 16 + q] = f2bf(acc[ct][r]);
        }
        // per-head projections: reduce over the 8 lanes of each head group
        float ps[4], pd[4];
        #pragma unroll
        for (int ct = 0; ct < 4; ct++) {
            float v = acc[ct][r];
            ps[ct] = v * atts[ct];
            pd[ct] = v * attd[ct];
        }
        #pragma unroll
        for (int m = 1; m < 8; m <<= 1) {
            #pragma unroll
            for (int ct = 0; ct < 4; ct++) {
                ps[ct] += __shfl_xor(ps[ct], m, 64);
                pd[ct] += __shfl_xor(pd[ct], m, 64);
            }
        }
        if (valid && (q & 7) == 0) {
            #pragma unroll
            for (int ct = 0; ct < 4; ct++) {
                int head = 2 * ct + (q >> 3);
                a_s[n * 8 + head] = ps[ct];
                a_d[n * 8 + head] = pd[ct];
            }
        }
    }
}

// ---------------- Phase B: dense adjacency build from buckets --------------
// 2 blocks per bucket; each builds 256 nodes' adj rows in LDS, writes dense.
#define BHALF 256
__global__ __launch_bounds__(256) void k_build(
    const unsigned int* __restrict__ ebuf, const int* __restrict__ bcnt,
    int* __restrict__ deg, unsigned short* __restrict__ adj)
{
    __shared__ unsigned short ladj[BHALF * CAP];  // 32 KB
    __shared__ int ldeg[BHALF];                   // 1 KB

    const int b    = blockIdx.x >> 1;
    const int half = blockIdx.x & 1;
    const int rlo  = half * BHALF;
    const int t    = threadIdx.x;

    if (t < BHALF) ldeg[t] = 0;
    __syncthreads();

    const int cnt = min(bcnt[b], BCAP);
    const unsigned int* eb = ebuf + (size_t)b * BCAP;
    for (int i = t; i < cnt; i += 256) {
        unsigned int v = eb[i];
        int drel = (v >> 16) & (BNODES - 1);
        unsigned int rr = (unsigned int)(drel - rlo);
        if (rr < BHALF) {
            int p = atomicAdd(&ldeg[rr], 1);
            if (p < CAP) ladj[rr * CAP + p] = (unsigned short)(v & 0xffffu);
        }
    }
    __syncthreads();

    const int n0 = b * BNODES + rlo;
    if (t < BHALF) {
        int n = n0 + t;
        if (n < NN) deg[n] = ldeg[t];
    }
    // adj rows: 256 rows x 128 B, coalesced uint4 stores (rows w/ deg<CAP
    // carry garbage past deg[n] -- never read by consumers)
    for (int i = t; i < BHALF * CAP / 8; i += 256) {
        int n = n0 + (i >> 3);
        if (n < NN)
            ((uint4*)(adj + (size_t)n * CAP))[i & 7] = ((const uint4*)ladj)[i];
    }
}

// ---------------- GAT aggregation: wave = 8 edge-slots x 8 col-octets ------
// 4-deep index preload + batched gather issue (4x MLP per wave).
__global__ __launch_bounds__(256) void k_aggr(
    const unsigned short* __restrict__ hb, const float* __restrict__ a_s,
    const float* __restrict__ a_d, const int* __restrict__ deg,
    const unsigned short* __restrict__ adj, const float* __restrict__ bias,
    const float* __restrict__ w_rel, const float* __restrict__ w_root,
    float* __restrict__ out, float* __restrict__ t_rel, float* __restrict__ t_root)
{
    const int wid  = threadIdx.x >> 6;
    const int lane = threadIdx.x & 63;
    const int g    = lane >> 3;     // edge slot 0..7
    const int c8   = lane & 7;      // head / col-octet 0..7
    const int n    = blockIdx.x * 4 + wid;
    if (n >= NN) return;

    const float ad_n = a_d[n * 8 + c8];

    float acc[8];
    #pragma unroll
    for (int k = 0; k < 8; k++) acc[k] = 0.f;
    float den = 0.f;

    // self-loop handled by edge slot 0
    if (g == 0) {
        float e0 = a_s[n * 8 + c8] + ad_n;
        e0 = e0 > 0.f ? e0 : 0.2f * e0;
        float ex0 = __expf(e0);
        uint4 hv = *(const uint4*)(hb + (size_t)n * OUTF + c8 * 8);
        acc[0] = ex0 * bf2f(hv.x & 0xffffu); acc[1] = ex0 * bf2f(hv.x >> 16);
        acc[2] = ex0 * bf2f(hv.y & 0xffffu); acc[3] = ex0 * bf2f(hv.y >> 16);
        acc[4] = ex0 * bf2f(hv.z & 0xffffu); acc[5] = ex0 * bf2f(hv.z >> 16);
        acc[6] = ex0 * bf2f(hv.w & 0xffffu); acc[7] = ex0 * bf2f(hv.w >> 16);
        den = ex0;
    }

    const int cnt = min(deg[n], CAP);
    const unsigned short* lst = adj + (size_t)n * CAP;

    // preload indices for 4 strided slots, then issue all gathers
    int sv[4];
    #pragma unroll
    for (int ii = 0; ii < 4; ii++) {
        int i = g + ii * 8;
        sv[ii] = (i < cnt) ? (int)lst[i] : -1;
    }
    float asl[4]; uint4 hvl[4];
    #pragma unroll
    for (int ii = 0; ii < 4; ii++) {
        int s = (sv[ii] >= 0) ? sv[ii] : n;    // clamp to hot self row
        asl[ii] = a_s[s * 8 + c8];
        hvl[ii] = *(const uint4*)(hb + (size_t)s * OUTF + c8 * 8);
    }
    #pragma unroll
    for (int ii = 0; ii < 4; ii++) {
        float e = asl[ii] + ad_n;
        e = e > 0.f ? e : 0.2f * e;
        float ex = (sv[ii] >= 0) ? __expf(e) : 0.f;
        uint4 hv = hvl[ii];
        acc[0] = fmaf(ex, bf2f(hv.x & 0xffffu), acc[0]);
        acc[1] = fmaf(ex, bf2f(hv.x >> 16),     acc[1]);
        acc[2] = fmaf(ex, bf2f(hv.y & 0xffffu), acc[2]);
        acc[3] = fmaf(ex, bf2f(hv.y >> 16),     acc[3]);
        acc[4] = fmaf(ex, bf2f(hv.z & 0xffffu), acc[4]);
        acc[5] = fmaf(ex, bf2f(hv.z >> 16),     acc[5]);
        acc[6] = fmaf(ex, bf2f(hv.w & 0xffffu), acc[6]);
        acc[7] = fmaf(ex, bf2f(hv.w >> 16),     acc[7]);
        den += ex;
    }
    // rare tail (deg > 32)
    for (int i = g + 32; i < cnt; i += 8) {
        int s = lst[i];
        float as = a_s[s * 8 + c8];
        uint4 hv = *(const uint4*)(hb + (size_t)s * OUTF + c8 * 8);
        float e = as + ad_n;
        e = e > 0.f ? e : 0.2f * e;
        float ex = __expf(e);
        acc[0] = fmaf(ex, bf2f(hv.x & 0xffffu), acc[0]);
        acc[1] = fmaf(ex, bf2f(hv.x >> 16),     acc[1]);
        acc[2] = fmaf(ex, bf2f(hv.y & 0xffffu), acc[2]);
        acc[3] = fmaf(ex, bf2f(hv.y >> 16),     acc[3]);
        acc[4] = fmaf(ex, bf2f(hv.z & 0xffffu), acc[4]);
        acc[5] = fmaf(ex, bf2f(hv.z >> 16),     acc[5]);
        acc[6] = fmaf(ex, bf2f(hv.w & 0xffffu), acc[6]);
        acc[7] = fmaf(ex, bf2f(hv.w >> 16),     acc[7]);
        den += ex;
    }

    // butterfly reduce across edge slots (g bits = lane bits 3..5)
    #pragma unroll
    for (int m = 8; m < 64; m <<= 1) {
        den += __shfl_xor(den, m, 64);
        #pragma unroll
        for (int k = 0; k < 8; k++) acc[k] += __shfl_xor(acc[k], m, 64);
    }

    const float inv = 1.f / (den + 1e-16f);
    float o[8];
    #pragma unroll
    for (int k = 0; k < 8; k++) o[k] = acc[k] * inv + bias[c8 * 8 + k];

    if (g == 0) {
        float4 o0 = make_float4(o[0], o[1], o[2], o[3]);
        float4 o1 = make_float4(o[4], o[5], o[6], o[7]);
        float4* op = (float4*)(out + (size_t)n * OUTF + c8 * 8);
        op[0] = o0; op[1] = o1;
    }

    // pooling-score projections: vr = sum_j o_j*w_rel_j (cols dup across g)
    float vr = 0.f, vt = 0.f;
    #pragma unroll
    for (int k = 0; k < 8; k++) {
        vr = fmaf(o[k], w_rel[c8 * 8 + k], vr);
        vt = fmaf(o[k], w_root[c8 * 8 + k], vt);
    }
    #pragma unroll
    for (int m = 1; m < 8; m <<= 1) {
        vr += __shfl_xor(vr, m, 64);
        vt += __shfl_xor(vt, m, 64);
    }
    if (lane == 0) { t_rel[n] = vr; t_root[n] = vt; }
}

// ---------------- fused pooling: score gather + softmax-numerator pool -----
__global__ __launch_bounds__(256) void k_score_pool(
    const int* __restrict__ deg, const unsigned short* __restrict__ adj,
    const float* __restrict__ t_rel, const float* __restrict__ t_root,
    const float* __restrict__ pool_b, const int* __restrict__ batch,
    const float* __restrict__ out,
    float* __restrict__ gden, float* __restrict__ g_num)
{
    __shared__ float ex_s[32];
    __shared__ int   b_s[32];

    const int wid  = threadIdx.x >> 6;
    const int lane = threadIdx.x & 63;
    const int sub  = lane >> 3;     // node within wave (0..7)
    const int g    = lane & 7;      // slot
    const int base_n = blockIdx.x * 32;
    const int n    = base_n + wid * 8 + sub;

    const int cnt = (n < NN) ? min(deg[n], CAP) : 0;
    const unsigned short* lst = adj + (size_t)n * CAP;
    float acc = 0.f;
    for (int i = g; i < cnt; i += 8) acc += t_rel[lst[i]];
    #pragma unroll
    for (int m = 1; m < 8; m <<= 1) acc += __shfl_xor(acc, m, 64);

    if (g == 0) {
        const int slot = wid * 8 + sub;
        if (n < NN) {
            float ex = __expf(acc + t_root[n] + pool_b[0]);
            ex_s[slot] = ex;
            b_s[slot]  = batch[n];
        } else {
            ex_s[slot] = 0.f;
            b_s[slot]  = -1;
        }
    }
    __syncthreads();

    if (threadIdx.x == 0) {           // gden run-length flush (batch sorted)
        float racc = 0.f;
        int bcur = -1;
        for (int i = 0; i < 32; i++) {
            int b = b_s[i];
            if (b != bcur) {
                if (bcur >= 0) atomicAdd(&gden[bcur], racc);
                bcur = b; racc = 0.f;
            }
            racc += ex_s[i];
        }
        if (bcur >= 0) atomicAdd(&gden[bcur], racc);
    }

    // phase 2: wave wid accumulates its 8 nodes; lane = feature j
    const int j = lane;
    float facc = 0.f;
    int bcur = -1;
    for (int i = 0; i < 8; i++) {
        const int slot = wid * 8 + i;
        const int n2 = base_n + slot;
        if (n2 >= NN) break;
        int b = b_s[slot];                         // wave-uniform
        if (b != bcur) {
            if (bcur >= 0) atomicAdd(&g_num[bcur * OUTF + j], facc);
            bcur = b; facc = 0.f;
        }
        facc = fmaf(out[(size_t)n2 * OUTF + j], ex_s[slot], facc);
    }
    if (bcur >= 0) atomicAdd(&g_num[bcur * OUTF + j], facc);
}

// ---------------- g[b,j] = g_num[b,j] / (gden[b] + eps) --------------------
__global__ __launch_bounds__(256) void k_gfinal(
    const float* __restrict__ g_num, const float* __restrict__ gden,
    float* __restrict__ g)
{
    int i = blockIdx.x * 256 + threadIdx.x;
    if (i < NG * OUTF) g[i] = g_num[i] / (gden[i >> 6] + 1e-16f);
}

extern "C" void kernel_launch(void* const* d_in, const int* in_sizes, int n_in,
                              void* d_out, int out_size, void* d_ws, size_t ws_size,
                              hipStream_t stream)
{
    const float* x        = (const float*)d_in[0];
    const int*   ei       = (const int*)  d_in[1];
    const int*   batch    = (const int*)  d_in[2];
    const float* W        = (const float*)d_in[3];
    const float* att_src  = (const float*)d_in[4];
    const float* att_dst  = (const float*)d_in[5];
    const float* bias     = (const float*)d_in[6];
    const float* w_rel    = (const float*)d_in[7];
    const float* pool_b   = (const float*)d_in[8];
    const float* w_root   = (const float*)d_in[9];

    float* out_nodes = (float*)d_out;                       // [NN,64]
    float* g_out     = (float*)d_out + (size_t)NN * OUTF;   // [NG,64]

    // workspace layout (bytes)
    char* base = (char*)d_ws;
    unsigned short* hb = (unsigned short*)(base);           //  6,400,000 B
    float* a_s       = (float*)(base +  6400000);           //  1,600,000 B
    float* a_d       = (float*)(base +  8000000);           //  1,600,000 B
    float* t_rel     = (float*)(base +  9600000);           //    200,000 B
    float* t_root    = (float*)(base +  9800000);           //    200,000 B
    float* gden      = (float*)(base + 10000000);           //      2,048 B
    float* g_num     = (float*)(base + 10002048);           //    131,072 B
    int*   deg       = (int*)  (base + 10133120);           //    200,000 B
    unsigned short* adjl = (unsigned short*)(base + 10333120); // 6,400,000 B
    unsigned int* ebuf = (unsigned int*)(base + 16733120);  //  3,612,672 B (98*9216*4)
    int*   bcnt      = (int*)  (base + 20345792);           //        512 B
    // total: 20,346,304 B

    hipMemsetAsync(bcnt, 0, 512, stream);   // bucket counters

    k_front<<<FRONT_BLOCKS, 256, 0, stream>>>(
        ei, bcnt, ebuf, gden, g_num,
        x, W, att_src, att_dst, hb, a_s, a_d);
    k_build<<<NPB * 2, 256, 0, stream>>>(ebuf, bcnt, deg, adjl);
    k_aggr<<<(NN + 3) / 4, 256, 0, stream>>>(hb, a_s, a_d, deg, adjl, bias,
                                             w_rel, w_root, out_nodes, t_rel, t_root);
    k_score_pool<<<(NN + 31) / 32, 256, 0, stream>>>(deg, adjl, t_rel, t_root,
                                                     pool_b, batch, out_nodes,
                                                     gden, g_num);
    k_gfinal<<<(NG * OUTF + 255) / 256, 256, 0, stream>>>(g_num, gden, g_out);
}